// Round 5
// baseline (394.340 us; speedup 1.0000x reference)
//
#include <hip/hip_runtime.h>

#define DIM 2048
#define NH 16
#define HD 128
#define BB 2
#define LL 2048
#define MROWS (BB * LL)   // 4096
#define NKV 2304          // 2048 q + 128 k + 128 v

typedef __attribute__((ext_vector_type(8))) short short8;
typedef __attribute__((ext_vector_type(4))) float floatx4;

__device__ inline ushort f2bf(float f) {
    union { float f; unsigned u; } v; v.f = f;
    unsigned r = v.u + 0x7FFFu + ((v.u >> 16) & 1u);
    return (ushort)(r >> 16);
}

#define GL16(g, l)                                                         \
    __builtin_amdgcn_global_load_lds(                                      \
        (const __attribute__((address_space(1))) unsigned int*)(g),        \
        (__attribute__((address_space(3))) unsigned int*)(l), 16, 0, 0)

// ---------------------------------------------------------------------------
// elementwise f32 -> bf16 (8 elems/thread)
// ---------------------------------------------------------------------------
__global__ __launch_bounds__(256) void conv_bf16(const float* __restrict__ in,
                                                 ushort* __restrict__ out) {
    size_t i = ((size_t)blockIdx.x * 256 + threadIdx.x) * 8;
    float4 a = *reinterpret_cast<const float4*>(in + i);
    float4 b = *reinterpret_cast<const float4*>(in + i + 4);
    ushort o[8] = {f2bf(a.x), f2bf(a.y), f2bf(a.z), f2bf(a.w),
                   f2bf(b.x), f2bf(b.y), f2bf(b.z), f2bf(b.w)};
    *reinterpret_cast<uint4*>(out + i) = *reinterpret_cast<uint4*>(o);
}

// ---------------------------------------------------------------------------
// merged weight prep: transpose+convert Wq,Wo,Wk,Wv in one launch.
// grid 2176 blocks of 256.
// ---------------------------------------------------------------------------
__global__ __launch_bounds__(256) void wprep(const float* __restrict__ Wq,
                                             const float* __restrict__ Wk,
                                             const float* __restrict__ Wv,
                                             const float* __restrict__ Wo,
                                             ushort* __restrict__ Wcatt,
                                             ushort* __restrict__ Wot) {
    __shared__ ushort T[64][72];
    const int bid = blockIdx.x;
    const float* in;
    ushort* out;
    int in_ld, c0, r0;
    const int out_ld = 2048;
    if (bid < 1024) {
        in = Wq; out = Wcatt; in_ld = 2048;
        c0 = (bid & 31) * 64; r0 = (bid >> 5) * 64;
    } else if (bid < 2048) {
        int t = bid - 1024;
        in = Wo; out = Wot; in_ld = 2048;
        c0 = (t & 31) * 64; r0 = (t >> 5) * 64;
    } else if (bid < 2112) {
        int t = bid - 2048;
        in = Wk; out = Wcatt + (size_t)2048 * 2048; in_ld = 128;
        c0 = (t & 1) * 64; r0 = (t >> 1) * 64;
    } else {
        int t = bid - 2112;
        in = Wv; out = Wcatt + (size_t)2176 * 2048; in_ld = 128;
        c0 = (t & 1) * 64; r0 = (t >> 1) * 64;
    }
    const int tid = threadIdx.x;
#pragma unroll
    for (int rep = 0; rep < 4; ++rep) {
        int idx = tid + rep * 256;
        int r = idx >> 4, c4 = idx & 15;
        float4 f = *reinterpret_cast<const float4*>(
            in + (size_t)(r0 + r) * in_ld + c0 + c4 * 4);
        T[r][c4 * 4 + 0] = f2bf(f.x);
        T[r][c4 * 4 + 1] = f2bf(f.y);
        T[r][c4 * 4 + 2] = f2bf(f.z);
        T[r][c4 * 4 + 3] = f2bf(f.w);
    }
    __syncthreads();
#pragma unroll
    for (int rep = 0; rep < 4; ++rep) {
        int idx = tid + rep * 256;
        int cr = idx >> 4, rc4 = idx & 15;
        uint a0 = (uint)T[rc4 * 4 + 0][cr] | ((uint)T[rc4 * 4 + 1][cr] << 16);
        uint a1 = (uint)T[rc4 * 4 + 2][cr] | ((uint)T[rc4 * 4 + 3][cr] << 16);
        uint2 val = {a0, a1};
        *reinterpret_cast<uint2*>(
            out + (size_t)(c0 + cr) * out_ld + r0 + rc4 * 4) = val;
    }
}

// ---------------------------------------------------------------------------
// bf16 MFMA GEMM: Y = A @ Bt^T. BM=BN=128, BK=32, 256 threads.
// XOR chunk swizzle: LDS slot (row, c) holds global chunk c ^ ((row>>1)&3)
// -> b128 fragment reads are exactly 2-way (free) instead of 8-way.
// ---------------------------------------------------------------------------
__global__ __launch_bounds__(256) void gemm_bf16(const ushort* __restrict__ A,
                                                 const ushort* __restrict__ Bt,
                                                 float* __restrict__ Y,
                                                 int K, int N) {
    __shared__ ushort As[128 * 32];
    __shared__ ushort Bs[128 * 32];
    const int tid = threadIdx.x;
    const int lane = tid & 63;
    const int w = tid >> 6;
    const int col = lane & 15, quad = lane >> 4;
    const int m0 = blockIdx.y * 128, n0 = blockIdx.x * 128;
    const int wm = (w >> 1) * 64, wn = (w & 1) * 64;

    floatx4 acc[4][4];
#pragma unroll
    for (int mt = 0; mt < 4; ++mt)
#pragma unroll
        for (int nt = 0; nt < 4; ++nt) acc[mt][nt] = (floatx4){0.f, 0.f, 0.f, 0.f};

    const int r = tid >> 2;                       // staged row 0..63
    const int cg = (tid & 3) ^ ((tid >> 3) & 3);  // swizzled global chunk
    const int sel = (col >> 1) & 3;               // read-side swizzle

    for (int k0 = 0; k0 < K; k0 += 32) {
        __syncthreads();
        GL16(A + (size_t)(m0 + r) * K + k0 + cg * 8, As + (size_t)tid * 8);
        GL16(A + (size_t)(m0 + 64 + r) * K + k0 + cg * 8,
             As + (size_t)(tid + 256) * 8);
        GL16(Bt + (size_t)(n0 + r) * K + k0 + cg * 8, Bs + (size_t)tid * 8);
        GL16(Bt + (size_t)(n0 + 64 + r) * K + k0 + cg * 8,
             Bs + (size_t)(tid + 256) * 8);
        __syncthreads();

        short8 af[4], bf[4];
#pragma unroll
        for (int mt = 0; mt < 4; ++mt)
            af[mt] = *reinterpret_cast<const short8*>(
                &As[(wm + mt * 16 + col) * 32 + (quad ^ sel) * 8]);
#pragma unroll
        for (int nt = 0; nt < 4; ++nt)
            bf[nt] = *reinterpret_cast<const short8*>(
                &Bs[(wn + nt * 16 + col) * 32 + (quad ^ sel) * 8]);
#pragma unroll
        for (int mt = 0; mt < 4; ++mt)
#pragma unroll
            for (int nt = 0; nt < 4; ++nt)
                acc[mt][nt] = __builtin_amdgcn_mfma_f32_16x16x32_bf16(
                    af[mt], bf[nt], acc[mt][nt], 0, 0, 0);
    }

#pragma unroll
    for (int mt = 0; mt < 4; ++mt)
#pragma unroll
        for (int nt = 0; nt < 4; ++nt)
#pragma unroll
            for (int rr = 0; rr < 4; ++rr)
                Y[(size_t)(m0 + wm + mt * 16 + quad * 4 + rr) * N + n0 + wn +
                  nt * 16 + col] = acc[mt][nt][rr];
}

// ---------------------------------------------------------------------------
// RoPE + RMSNorm: fp32 in (token stride in_ld, head stride HD) -> bf16 out.
// ---------------------------------------------------------------------------
__global__ __launch_bounds__(256) void rope_rms_bf16(const float* __restrict__ in,
                                                     ushort* __restrict__ outb,
                                                     const float* __restrict__ cosb,
                                                     const float* __restrict__ sinb,
                                                     int heads, int nrows,
                                                     int in_ld) {
    int row = blockIdx.x * 4 + (threadIdx.x >> 6);
    int lane = threadIdx.x & 63;
    if (row >= nrows) return;
    int token = row / heads, head = row % heads;
    int l = token & (LL - 1);
    const float* p = in + (size_t)token * in_ld + head * HD;
    float x1 = p[lane];
    float x2 = p[lane + 64];
    float c = cosb[l * 64 + lane];
    float s = sinb[l * 64 + lane];
    float o1 = x1 * c + x2 * s;
    float o2 = -x1 * s + x2 * c;
    float ss = o1 * o1 + o2 * o2;
#pragma unroll
    for (int off = 32; off > 0; off >>= 1) ss += __shfl_xor(ss, off);
    float r = rsqrtf(ss * (1.0f / 128.0f) + 1e-6f);
    outb[(size_t)row * HD + lane] = f2bf(o1 * r);
    outb[(size_t)row * HD + lane + 64] = f2bf(o2 * r);
}

// ---------------------------------------------------------------------------
// V transpose + bf16: in f32 (B*L, in_ld) cols 0..127 -> vt (B,128,L) bf16.
// ---------------------------------------------------------------------------
__global__ __launch_bounds__(256) void vtrans(const float* __restrict__ v,
                                              ushort* __restrict__ vt,
                                              int in_ld) {
    __shared__ ushort T[64][72];
    const int l0 = blockIdx.x * 64, d0 = blockIdx.y * 64, b = blockIdx.z;
    const int tid = threadIdx.x;
#pragma unroll
    for (int rep = 0; rep < 4; ++rep) {
        int idx = tid + rep * 256;
        int r = idx >> 4, c4 = idx & 15;
        float4 f = *reinterpret_cast<const float4*>(
            v + (size_t)(b * LL + l0 + r) * in_ld + d0 + c4 * 4);
        T[r][c4 * 4 + 0] = f2bf(f.x);
        T[r][c4 * 4 + 1] = f2bf(f.y);
        T[r][c4 * 4 + 2] = f2bf(f.z);
        T[r][c4 * 4 + 3] = f2bf(f.w);
    }
    __syncthreads();
#pragma unroll
    for (int rep = 0; rep < 4; ++rep) {
        int idx = tid + rep * 256;
        int dr = idx >> 4, lc4 = idx & 15;
        uint a0 = (uint)T[lc4 * 4 + 0][dr] | ((uint)T[lc4 * 4 + 1][dr] << 16);
        uint a1 = (uint)T[lc4 * 4 + 2][dr] | ((uint)T[lc4 * 4 + 3][dr] << 16);
        uint2 val = {a0, a1};
        *reinterpret_cast<uint2*>(
            vt + (size_t)(b * HD + d0 + dr) * LL + l0 + lc4 * 4) = val;
    }
}

// ---------------------------------------------------------------------------
// Flash-style causal MQA attention, bf16 MFMA 16x16x32, load-balanced pairs.
// log2-domain softmax; mask only on the diagonal tile; gated O-rescale.
// ---------------------------------------------------------------------------
__global__ __launch_bounds__(256) void flash_mfma(const ushort* __restrict__ qb,
                                                  const ushort* __restrict__ kb,
                                                  const ushort* __restrict__ vt,
                                                  ushort* __restrict__ aob) {
    __shared__ ushort Ks[64][136];
    __shared__ ushort VTs[128][72];
    __shared__ ushort Ps[4][16][72];

    const int tid = threadIdx.x;
    const int w = tid >> 6, lane = tid & 63;
    const int col = lane & 15, quad = lane >> 4;
    const int pairIdx = blockIdx.x, bh = blockIdx.y;
    const int b = bh >> 4, h = bh & 15;
    // scale * log2(e): softmax computed in exp2 domain
    const float scl2 = 0.08838834764831845f * 1.44269504088896340736f;

    for (int sp = 0; sp < 2; ++sp) {
        const int qt = sp ? (31 - pairIdx) : pairIdx;
        const int q0 = qt * 64;

        const ushort* qrow =
            qb + ((size_t)(b * LL + q0 + w * 16 + col) * NH + h) * HD;
        short8 aq[4];
#pragma unroll
        for (int kc = 0; kc < 4; ++kc)
            aq[kc] = *reinterpret_cast<const short8*>(qrow + kc * 32 + quad * 8);

        float mrow[4], lrow[4];
        floatx4 oacc[8];
#pragma unroll
        for (int rr = 0; rr < 4; ++rr) { mrow[rr] = -1e30f; lrow[rr] = 0.0f; }
#pragma unroll
        for (int dt = 0; dt < 8; ++dt) oacc[dt] = (floatx4){0.f, 0.f, 0.f, 0.f};

        const int ntiles = qt + 1;
        for (int kt = 0; kt < ntiles; ++kt) {
            const int k0 = kt * 64;
            __syncthreads();
#pragma unroll
            for (int rep = 0; rep < 4; ++rep) {
                int idx = tid + rep * 256;
                int r = idx >> 4, c8 = idx & 15;
                float4 src = *reinterpret_cast<const float4*>(
                    kb + (size_t)(b * LL + k0 + r) * HD + c8 * 8);
                *reinterpret_cast<float4*>(&Ks[r][c8 * 8]) = src;
            }
#pragma unroll
            for (int rep = 0; rep < 4; ++rep) {
                int idx = tid + rep * 256;
                int d = idx >> 3, k8 = idx & 7;
                float4 src = *reinterpret_cast<const float4*>(
                    vt + (size_t)(b * HD + d) * LL + k0 + k8 * 8);
                *reinterpret_cast<float4*>(&VTs[d][k8 * 8]) = src;
            }
            __syncthreads();

            // S = Q K^T
            floatx4 sacc[4];
#pragma unroll
            for (int nt = 0; nt < 4; ++nt)
                sacc[nt] = (floatx4){0.f, 0.f, 0.f, 0.f};
#pragma unroll
            for (int nt = 0; nt < 4; ++nt) {
#pragma unroll
                for (int kc = 0; kc < 4; ++kc) {
                    short8 bk = *reinterpret_cast<const short8*>(
                        &Ks[nt * 16 + col][kc * 32 + quad * 8]);
                    sacc[nt] = __builtin_amdgcn_mfma_f32_16x16x32_bf16(
                        aq[kc], bk, sacc[nt], 0, 0, 0);
                }
            }

            // scale to log2 domain (+ mask only on the diagonal tile)
            float cmax[4] = {-1e30f, -1e30f, -1e30f, -1e30f};
            if (kt == qt) {
#pragma unroll
                for (int nt = 0; nt < 4; ++nt) {
                    int kj = k0 + nt * 16 + col;
#pragma unroll
                    for (int rr = 0; rr < 4; ++rr) {
                        int qi = q0 + w * 16 + quad * 4 + rr;
                        float s = sacc[nt][rr] * scl2;
                        s = (kj <= qi) ? s : -1e30f;
                        sacc[nt][rr] = s;
                        cmax[rr] = fmaxf(cmax[rr], s);
                    }
                }
            } else {
#pragma unroll
                for (int nt = 0; nt < 4; ++nt)
#pragma unroll
                    for (int rr = 0; rr < 4; ++rr) {
                        float s = sacc[nt][rr] * scl2;
                        sacc[nt][rr] = s;
                        cmax[rr] = fmaxf(cmax[rr], s);
                    }
            }
#pragma unroll
            for (int off = 1; off < 16; off <<= 1)
#pragma unroll
                for (int rr = 0; rr < 4; ++rr)
                    cmax[rr] = fmaxf(cmax[rr], __shfl_xor(cmax[rr], off));
            float alpha[4];
#pragma unroll
            for (int rr = 0; rr < 4; ++rr) {
                float mn = fmaxf(mrow[rr], cmax[rr]);
                alpha[rr] = exp2f(mrow[rr] - mn);
                mrow[rr] = mn;
            }
            float psum[4] = {0.f, 0.f, 0.f, 0.f};
#pragma unroll
            for (int nt = 0; nt < 4; ++nt)
#pragma unroll
                for (int rr = 0; rr < 4; ++rr) {
                    float p = exp2f(sacc[nt][rr] - mrow[rr]);
                    sacc[nt][rr] = p;
                    psum[rr] += p;
                }
#pragma unroll
            for (int rr = 0; rr < 4; ++rr)
                lrow[rr] = lrow[rr] * alpha[rr] + psum[rr];
            // gated O-rescale: alpha==1 on most tiles once the max settles
            if (__any(alpha[0] != 1.0f || alpha[1] != 1.0f ||
                      alpha[2] != 1.0f || alpha[3] != 1.0f)) {
#pragma unroll
                for (int dt = 0; dt < 8; ++dt)
#pragma unroll
                    for (int rr = 0; rr < 4; ++rr) oacc[dt][rr] *= alpha[rr];
            }

            // P: C-layout -> LDS -> A-layout (per-wave buffer)
#pragma unroll
            for (int nt = 0; nt < 4; ++nt)
#pragma unroll
                for (int rr = 0; rr < 4; ++rr)
                    Ps[w][quad * 4 + rr][nt * 16 + col] = f2bf(sacc[nt][rr]);
            asm volatile("s_waitcnt lgkmcnt(0)" ::: "memory");

            // O += P V
#pragma unroll
            for (int kt2 = 0; kt2 < 2; ++kt2) {
                short8 ap = *reinterpret_cast<const short8*>(
                    &Ps[w][col][kt2 * 32 + quad * 8]);
#pragma unroll
                for (int dt = 0; dt < 8; ++dt) {
                    short8 bv = *reinterpret_cast<const short8*>(
                        &VTs[dt * 16 + col][kt2 * 32 + quad * 8]);
                    oacc[dt] = __builtin_amdgcn_mfma_f32_16x16x32_bf16(
                        ap, bv, oacc[dt], 0, 0, 0);
                }
            }
        }

        // epilogue
#pragma unroll
        for (int off = 1; off < 16; off <<= 1)
#pragma unroll
            for (int rr = 0; rr < 4; ++rr)
                lrow[rr] += __shfl_xor(lrow[rr], off);
        float inv[4];
#pragma unroll
        for (int rr = 0; rr < 4; ++rr) inv[rr] = 1.0f / lrow[rr];
#pragma unroll
        for (int dt = 0; dt < 8; ++dt)
#pragma unroll
            for (int rr = 0; rr < 4; ++rr)
                aob[((size_t)(b * LL + q0 + w * 16 + quad * 4 + rr) * NH + h) *
                        HD + dt * 16 + col] = f2bf(oacc[dt][rr] * inv[rr]);
    }
}

// ---------------------------------------------------------------------------
extern "C" void kernel_launch(void* const* d_in, const int* in_sizes, int n_in,
                              void* d_out, int out_size, void* d_ws,
                              size_t ws_size, hipStream_t stream) {
    const float* x    = (const float*)d_in[0];
    const float* cosb = (const float*)d_in[1];
    const float* sinb = (const float*)d_in[2];
    const float* Wq   = (const float*)d_in[3];
    const float* Wk   = (const float*)d_in[4];
    const float* Wv   = (const float*)d_in[5];
    const float* Wo   = (const float*)d_in[6];
    float* out = (float*)d_out;

    float* qkv  = (float*)d_ws;                         // M*2304 f32
    ushort* xb  = (ushort*)(qkv + (size_t)MROWS * NKV); // M*DIM bf16
    ushort* qb  = xb + (size_t)MROWS * DIM;             // M*DIM bf16
    ushort* kb  = qb + (size_t)MROWS * DIM;             // M*HD bf16
    ushort* vt  = kb + (size_t)MROWS * HD;              // M*HD bf16 (B,D,L)
    ushort* aob = vt + (size_t)MROWS * HD;              // M*DIM bf16
    ushort* Wcatt = aob + (size_t)MROWS * DIM;          // 2304*2048 bf16
    ushort* Wot   = Wcatt + (size_t)NKV * DIM;          // 2048*2048 bf16

    conv_bf16<<<dim3(MROWS * DIM / (256 * 8)), 256, 0, stream>>>(x, xb);
    wprep<<<dim3(2176), 256, 0, stream>>>(Wq, Wk, Wv, Wo, Wcatt, Wot);

    // fused q|k|v projection: (M,2048) @ (2048,2304)
    gemm_bf16<<<dim3(NKV / 128, MROWS / 128), 256, 0, stream>>>(xb, Wcatt, qkv,
                                                                DIM, NKV);

    // RoPE + RMSNorm -> bf16
    rope_rms_bf16<<<dim3(MROWS * NH / 4), 256, 0, stream>>>(
        qkv, qb, cosb, sinb, NH, MROWS * NH, NKV);
    rope_rms_bf16<<<dim3(MROWS / 4), 256, 0, stream>>>(
        qkv + DIM, kb, cosb, sinb, 1, MROWS, NKV);
    vtrans<<<dim3(LL / 64, 2, BB), 256, 0, stream>>>(qkv + DIM + HD, vt, NKV);

    // causal MQA attention
    flash_mfma<<<dim3(LL / 128, BB * NH), 256, 0, stream>>>(qb, kb, vt, aob);

    // output projection
    gemm_bf16<<<dim3(DIM / 128, MROWS / 128), 256, 0, stream>>>(aob, Wot, out,
                                                                DIM, DIM);
}

// Round 6
// 347.224 us; speedup vs baseline: 1.1357x; 1.1357x over previous
//
#include <hip/hip_runtime.h>

#define DIM 2048
#define NH 16
#define HD 128
#define BB 2
#define LL 2048
#define MROWS (BB * LL)   // 4096
#define NKV 2304          // 2048 q + 128 k + 128 v

typedef __attribute__((ext_vector_type(8))) short short8;
typedef __attribute__((ext_vector_type(4))) float floatx4;

__device__ inline ushort f2bf(float f) {
    union { float f; unsigned u; } v; v.f = f;
    unsigned r = v.u + 0x7FFFu + ((v.u >> 16) & 1u);
    return (ushort)(r >> 16);
}

#define GL16(g, l)                                                         \
    __builtin_amdgcn_global_load_lds(                                      \
        (const __attribute__((address_space(1))) unsigned int*)(g),        \
        (__attribute__((address_space(3))) unsigned int*)(l), 16, 0, 0)

// ---------------------------------------------------------------------------
// elementwise f32 -> bf16 (8 elems/thread)
// ---------------------------------------------------------------------------
__global__ __launch_bounds__(256) void conv_bf16(const float* __restrict__ in,
                                                 ushort* __restrict__ out) {
    size_t i = ((size_t)blockIdx.x * 256 + threadIdx.x) * 8;
    float4 a = *reinterpret_cast<const float4*>(in + i);
    float4 b = *reinterpret_cast<const float4*>(in + i + 4);
    ushort o[8] = {f2bf(a.x), f2bf(a.y), f2bf(a.z), f2bf(a.w),
                   f2bf(b.x), f2bf(b.y), f2bf(b.z), f2bf(b.w)};
    *reinterpret_cast<uint4*>(out + i) = *reinterpret_cast<uint4*>(o);
}

// ---------------------------------------------------------------------------
// merged weight prep: transpose+convert Wq,Wo,Wk,Wv in one launch.
// ---------------------------------------------------------------------------
__global__ __launch_bounds__(256) void wprep(const float* __restrict__ Wq,
                                             const float* __restrict__ Wk,
                                             const float* __restrict__ Wv,
                                             const float* __restrict__ Wo,
                                             ushort* __restrict__ Wcatt,
                                             ushort* __restrict__ Wot) {
    __shared__ ushort T[64][72];
    const int bid = blockIdx.x;
    const float* in;
    ushort* out;
    int in_ld, c0, r0;
    const int out_ld = 2048;
    if (bid < 1024) {
        in = Wq; out = Wcatt; in_ld = 2048;
        c0 = (bid & 31) * 64; r0 = (bid >> 5) * 64;
    } else if (bid < 2048) {
        int t = bid - 1024;
        in = Wo; out = Wot; in_ld = 2048;
        c0 = (t & 31) * 64; r0 = (t >> 5) * 64;
    } else if (bid < 2112) {
        int t = bid - 2048;
        in = Wk; out = Wcatt + (size_t)2048 * 2048; in_ld = 128;
        c0 = (t & 1) * 64; r0 = (t >> 1) * 64;
    } else {
        int t = bid - 2112;
        in = Wv; out = Wcatt + (size_t)2176 * 2048; in_ld = 128;
        c0 = (t & 1) * 64; r0 = (t >> 1) * 64;
    }
    const int tid = threadIdx.x;
#pragma unroll
    for (int rep = 0; rep < 4; ++rep) {
        int idx = tid + rep * 256;
        int r = idx >> 4, c4 = idx & 15;
        float4 f = *reinterpret_cast<const float4*>(
            in + (size_t)(r0 + r) * in_ld + c0 + c4 * 4);
        T[r][c4 * 4 + 0] = f2bf(f.x);
        T[r][c4 * 4 + 1] = f2bf(f.y);
        T[r][c4 * 4 + 2] = f2bf(f.z);
        T[r][c4 * 4 + 3] = f2bf(f.w);
    }
    __syncthreads();
#pragma unroll
    for (int rep = 0; rep < 4; ++rep) {
        int idx = tid + rep * 256;
        int cr = idx >> 4, rc4 = idx & 15;
        uint a0 = (uint)T[rc4 * 4 + 0][cr] | ((uint)T[rc4 * 4 + 1][cr] << 16);
        uint a1 = (uint)T[rc4 * 4 + 2][cr] | ((uint)T[rc4 * 4 + 3][cr] << 16);
        uint2 val = {a0, a1};
        *reinterpret_cast<uint2*>(
            out + (size_t)(c0 + cr) * out_ld + r0 + rc4 * 4) = val;
    }
}

// ---------------------------------------------------------------------------
// bf16 MFMA GEMM: Y = A @ Bt^T. BM=BN=128, BK=64, 256 threads (4 waves).
// 32 KB LDS, 8x GL16/iter, XOR chunk swizzle (chunk ^ (row&7)) so that
// 128-B LDS rows don't alias fragment reads onto one bank group.
// ---------------------------------------------------------------------------
__global__ __launch_bounds__(256) void gemm_bf16(const ushort* __restrict__ A,
                                                 const ushort* __restrict__ Bt,
                                                 float* __restrict__ Y,
                                                 int K, int N) {
    __shared__ ushort As[128 * 64];   // 16 KB
    __shared__ ushort Bs[128 * 64];   // 16 KB
    const int tid = threadIdx.x;
    const int lane = tid & 63;
    const int w = tid >> 6;
    const int col = lane & 15, quad = lane >> 4;
    const int m0 = blockIdx.y * 128, n0 = blockIdx.x * 128;
    const int wm = (w >> 1) * 64, wn = (w & 1) * 64;

    floatx4 acc[4][4];
#pragma unroll
    for (int mt = 0; mt < 4; ++mt)
#pragma unroll
        for (int nt = 0; nt < 4; ++nt) acc[mt][nt] = (floatx4){0.f, 0.f, 0.f, 0.f};

    const int sr = tid >> 3;                    // staging row 0..31 (per call)
    const int cg = (tid & 7) ^ (sr & 7);        // swizzled global chunk 0..7
    const int sel = col & 7;                    // read-side unswizzle

    for (int k0 = 0; k0 < K; k0 += 64) {
        __syncthreads();
#pragma unroll
        for (int j = 0; j < 4; ++j)
            GL16(A + (size_t)(m0 + j * 32 + sr) * K + k0 + cg * 8,
                 As + (size_t)(j * 2048 + tid * 8));
#pragma unroll
        for (int j = 0; j < 4; ++j)
            GL16(Bt + (size_t)(n0 + j * 32 + sr) * K + k0 + cg * 8,
                 Bs + (size_t)(j * 2048 + tid * 8));
        __syncthreads();

#pragma unroll
        for (int kk = 0; kk < 2; ++kk) {
            short8 af[4], bf[4];
#pragma unroll
            for (int mt = 0; mt < 4; ++mt)
                af[mt] = *reinterpret_cast<const short8*>(
                    &As[(wm + mt * 16 + col) * 64 +
                        ((kk * 4 + quad) ^ sel) * 8]);
#pragma unroll
            for (int nt = 0; nt < 4; ++nt)
                bf[nt] = *reinterpret_cast<const short8*>(
                    &Bs[(wn + nt * 16 + col) * 64 +
                        ((kk * 4 + quad) ^ sel) * 8]);
#pragma unroll
            for (int mt = 0; mt < 4; ++mt)
#pragma unroll
                for (int nt = 0; nt < 4; ++nt)
                    acc[mt][nt] = __builtin_amdgcn_mfma_f32_16x16x32_bf16(
                        af[mt], bf[nt], acc[mt][nt], 0, 0, 0);
        }
    }

#pragma unroll
    for (int mt = 0; mt < 4; ++mt)
#pragma unroll
        for (int nt = 0; nt < 4; ++nt)
#pragma unroll
            for (int rr = 0; rr < 4; ++rr)
                Y[(size_t)(m0 + wm + mt * 16 + quad * 4 + rr) * N + n0 + wn +
                  nt * 16 + col] = acc[mt][nt][rr];
}

// ---------------------------------------------------------------------------
// RoPE + RMSNorm: fp32 in (token stride in_ld, head stride HD) -> bf16 out.
// ---------------------------------------------------------------------------
__global__ __launch_bounds__(256) void rope_rms_bf16(const float* __restrict__ in,
                                                     ushort* __restrict__ outb,
                                                     const float* __restrict__ cosb,
                                                     const float* __restrict__ sinb,
                                                     int heads, int nrows,
                                                     int in_ld) {
    int row = blockIdx.x * 4 + (threadIdx.x >> 6);
    int lane = threadIdx.x & 63;
    if (row >= nrows) return;
    int token = row / heads, head = row % heads;
    int l = token & (LL - 1);
    const float* p = in + (size_t)token * in_ld + head * HD;
    float x1 = p[lane];
    float x2 = p[lane + 64];
    float c = cosb[l * 64 + lane];
    float s = sinb[l * 64 + lane];
    float o1 = x1 * c + x2 * s;
    float o2 = -x1 * s + x2 * c;
    float ss = o1 * o1 + o2 * o2;
#pragma unroll
    for (int off = 32; off > 0; off >>= 1) ss += __shfl_xor(ss, off);
    float r = rsqrtf(ss * (1.0f / 128.0f) + 1e-6f);
    outb[(size_t)row * HD + lane] = f2bf(o1 * r);
    outb[(size_t)row * HD + lane + 64] = f2bf(o2 * r);
}

// ---------------------------------------------------------------------------
// V transpose + bf16: in f32 (B*L, in_ld) cols 0..127 -> vt (B,128,L) bf16.
// ---------------------------------------------------------------------------
__global__ __launch_bounds__(256) void vtrans(const float* __restrict__ v,
                                              ushort* __restrict__ vt,
                                              int in_ld) {
    __shared__ ushort T[64][72];
    const int l0 = blockIdx.x * 64, d0 = blockIdx.y * 64, b = blockIdx.z;
    const int tid = threadIdx.x;
#pragma unroll
    for (int rep = 0; rep < 4; ++rep) {
        int idx = tid + rep * 256;
        int r = idx >> 4, c4 = idx & 15;
        float4 f = *reinterpret_cast<const float4*>(
            v + (size_t)(b * LL + l0 + r) * in_ld + d0 + c4 * 4);
        T[r][c4 * 4 + 0] = f2bf(f.x);
        T[r][c4 * 4 + 1] = f2bf(f.y);
        T[r][c4 * 4 + 2] = f2bf(f.z);
        T[r][c4 * 4 + 3] = f2bf(f.w);
    }
    __syncthreads();
#pragma unroll
    for (int rep = 0; rep < 4; ++rep) {
        int idx = tid + rep * 256;
        int dr = idx >> 4, lc4 = idx & 15;
        uint a0 = (uint)T[lc4 * 4 + 0][dr] | ((uint)T[lc4 * 4 + 1][dr] << 16);
        uint a1 = (uint)T[lc4 * 4 + 2][dr] | ((uint)T[lc4 * 4 + 3][dr] << 16);
        uint2 val = {a0, a1};
        *reinterpret_cast<uint2*>(
            vt + (size_t)(b * HD + d0 + dr) * LL + l0 + lc4 * 4) = val;
    }
}

// ---------------------------------------------------------------------------
// Flash-style causal MQA attention, bf16 MFMA 16x16x32, load-balanced pairs.
// (Exact R4 body — R5's branchy softmax variants regressed; reverted.)
// ---------------------------------------------------------------------------
__global__ __launch_bounds__(256) void flash_mfma(const ushort* __restrict__ qb,
                                                  const ushort* __restrict__ kb,
                                                  const ushort* __restrict__ vt,
                                                  ushort* __restrict__ aob) {
    __shared__ ushort Ks[64][136];
    __shared__ ushort VTs[128][72];
    __shared__ ushort Ps[4][16][72];

    const int tid = threadIdx.x;
    const int w = tid >> 6, lane = tid & 63;
    const int col = lane & 15, quad = lane >> 4;
    const int pairIdx = blockIdx.x, bh = blockIdx.y;
    const int b = bh >> 4, h = bh & 15;
    const float scale = 0.08838834764831845f;  // 1/sqrt(128)

    for (int sp = 0; sp < 2; ++sp) {
        const int qt = sp ? (31 - pairIdx) : pairIdx;
        const int q0 = qt * 64;

        const ushort* qrow =
            qb + ((size_t)(b * LL + q0 + w * 16 + col) * NH + h) * HD;
        short8 aq[4];
#pragma unroll
        for (int kc = 0; kc < 4; ++kc)
            aq[kc] = *reinterpret_cast<const short8*>(qrow + kc * 32 + quad * 8);

        float mrow[4], lrow[4];
        floatx4 oacc[8];
#pragma unroll
        for (int rr = 0; rr < 4; ++rr) { mrow[rr] = -1e30f; lrow[rr] = 0.0f; }
#pragma unroll
        for (int dt = 0; dt < 8; ++dt) oacc[dt] = (floatx4){0.f, 0.f, 0.f, 0.f};

        const int ntiles = qt + 1;
        for (int kt = 0; kt < ntiles; ++kt) {
            const int k0 = kt * 64;
            __syncthreads();
#pragma unroll
            for (int rep = 0; rep < 4; ++rep) {
                int idx = tid + rep * 256;
                int r = idx >> 4, c8 = idx & 15;
                float4 src = *reinterpret_cast<const float4*>(
                    kb + (size_t)(b * LL + k0 + r) * HD + c8 * 8);
                *reinterpret_cast<float4*>(&Ks[r][c8 * 8]) = src;
            }
#pragma unroll
            for (int rep = 0; rep < 4; ++rep) {
                int idx = tid + rep * 256;
                int d = idx >> 3, k8 = idx & 7;
                float4 src = *reinterpret_cast<const float4*>(
                    vt + (size_t)(b * HD + d) * LL + k0 + k8 * 8);
                *reinterpret_cast<float4*>(&VTs[d][k8 * 8]) = src;
            }
            __syncthreads();

            // S = Q K^T
            floatx4 sacc[4];
#pragma unroll
            for (int nt = 0; nt < 4; ++nt)
                sacc[nt] = (floatx4){0.f, 0.f, 0.f, 0.f};
#pragma unroll
            for (int nt = 0; nt < 4; ++nt) {
#pragma unroll
                for (int kc = 0; kc < 4; ++kc) {
                    short8 bk = *reinterpret_cast<const short8*>(
                        &Ks[nt * 16 + col][kc * 32 + quad * 8]);
                    sacc[nt] = __builtin_amdgcn_mfma_f32_16x16x32_bf16(
                        aq[kc], bk, sacc[nt], 0, 0, 0);
                }
            }

            // scale + causal mask + running max
            float cmax[4] = {-1e30f, -1e30f, -1e30f, -1e30f};
#pragma unroll
            for (int nt = 0; nt < 4; ++nt) {
                int kj = k0 + nt * 16 + col;
#pragma unroll
                for (int rr = 0; rr < 4; ++rr) {
                    int qi = q0 + w * 16 + quad * 4 + rr;
                    float s = sacc[nt][rr] * scale;
                    s = (kj <= qi) ? s : -1e30f;
                    sacc[nt][rr] = s;
                    cmax[rr] = fmaxf(cmax[rr], s);
                }
            }
#pragma unroll
            for (int off = 1; off < 16; off <<= 1)
#pragma unroll
                for (int rr = 0; rr < 4; ++rr)
                    cmax[rr] = fmaxf(cmax[rr], __shfl_xor(cmax[rr], off));
            float alpha[4];
#pragma unroll
            for (int rr = 0; rr < 4; ++rr) {
                float mn = fmaxf(mrow[rr], cmax[rr]);
                alpha[rr] = __expf(mrow[rr] - mn);
                mrow[rr] = mn;
            }
            float psum[4] = {0.f, 0.f, 0.f, 0.f};
#pragma unroll
            for (int nt = 0; nt < 4; ++nt)
#pragma unroll
                for (int rr = 0; rr < 4; ++rr) {
                    float p = __expf(sacc[nt][rr] - mrow[rr]);
                    sacc[nt][rr] = p;
                    psum[rr] += p;
                }
#pragma unroll
            for (int rr = 0; rr < 4; ++rr)
                lrow[rr] = lrow[rr] * alpha[rr] + psum[rr];
#pragma unroll
            for (int dt = 0; dt < 8; ++dt)
#pragma unroll
                for (int rr = 0; rr < 4; ++rr) oacc[dt][rr] *= alpha[rr];

            // P: C-layout -> LDS -> A-layout (per-wave buffer)
#pragma unroll
            for (int nt = 0; nt < 4; ++nt)
#pragma unroll
                for (int rr = 0; rr < 4; ++rr)
                    Ps[w][quad * 4 + rr][nt * 16 + col] = f2bf(sacc[nt][rr]);
            asm volatile("s_waitcnt lgkmcnt(0)" ::: "memory");

            // O += P V
#pragma unroll
            for (int kt2 = 0; kt2 < 2; ++kt2) {
                short8 ap = *reinterpret_cast<const short8*>(
                    &Ps[w][col][kt2 * 32 + quad * 8]);
#pragma unroll
                for (int dt = 0; dt < 8; ++dt) {
                    short8 bv = *reinterpret_cast<const short8*>(
                        &VTs[dt * 16 + col][kt2 * 32 + quad * 8]);
                    oacc[dt] = __builtin_amdgcn_mfma_f32_16x16x32_bf16(
                        ap, bv, oacc[dt], 0, 0, 0);
                }
            }
        }

        // epilogue: reduce per-lane l across the 16 row lanes, store bf16
#pragma unroll
        for (int off = 1; off < 16; off <<= 1)
#pragma unroll
            for (int rr = 0; rr < 4; ++rr)
                lrow[rr] += __shfl_xor(lrow[rr], off);
        float inv[4];
#pragma unroll
        for (int rr = 0; rr < 4; ++rr) inv[rr] = 1.0f / lrow[rr];
#pragma unroll
        for (int dt = 0; dt < 8; ++dt)
#pragma unroll
            for (int rr = 0; rr < 4; ++rr)
                aob[((size_t)(b * LL + q0 + w * 16 + quad * 4 + rr) * NH + h) *
                        HD + dt * 16 + col] = f2bf(oacc[dt][rr] * inv[rr]);
    }
}

// ---------------------------------------------------------------------------
extern "C" void kernel_launch(void* const* d_in, const int* in_sizes, int n_in,
                              void* d_out, int out_size, void* d_ws,
                              size_t ws_size, hipStream_t stream) {
    const float* x    = (const float*)d_in[0];
    const float* cosb = (const float*)d_in[1];
    const float* sinb = (const float*)d_in[2];
    const float* Wq   = (const float*)d_in[3];
    const float* Wk   = (const float*)d_in[4];
    const float* Wv   = (const float*)d_in[5];
    const float* Wo   = (const float*)d_in[6];
    float* out = (float*)d_out;

    float* qkv  = (float*)d_ws;                         // M*2304 f32
    ushort* xb  = (ushort*)(qkv + (size_t)MROWS * NKV); // M*DIM bf16
    ushort* qb  = xb + (size_t)MROWS * DIM;             // M*DIM bf16
    ushort* kb  = qb + (size_t)MROWS * DIM;             // M*HD bf16
    ushort* vt  = kb + (size_t)MROWS * HD;              // M*HD bf16 (B,D,L)
    ushort* aob = vt + (size_t)MROWS * HD;              // M*DIM bf16
    ushort* Wcatt = aob + (size_t)MROWS * DIM;          // 2304*2048 bf16
    ushort* Wot   = Wcatt + (size_t)NKV * DIM;          // 2048*2048 bf16

    conv_bf16<<<dim3(MROWS * DIM / (256 * 8)), 256, 0, stream>>>(x, xb);
    wprep<<<dim3(2176), 256, 0, stream>>>(Wq, Wk, Wv, Wo, Wcatt, Wot);

    // fused q|k|v projection: (M,2048) @ (2048,2304)
    gemm_bf16<<<dim3(NKV / 128, MROWS / 128), 256, 0, stream>>>(xb, Wcatt, qkv,
                                                                DIM, NKV);

    // RoPE + RMSNorm -> bf16
    rope_rms_bf16<<<dim3(MROWS * NH / 4), 256, 0, stream>>>(
        qkv, qb, cosb, sinb, NH, MROWS * NH, NKV);
    rope_rms_bf16<<<dim3(MROWS / 4), 256, 0, stream>>>(
        qkv + DIM, kb, cosb, sinb, 1, MROWS, NKV);
    vtrans<<<dim3(LL / 64, 2, BB), 256, 0, stream>>>(qkv + DIM + HD, vt, NKV);

    // causal MQA attention
    flash_mfma<<<dim3(LL / 128, BB * NH), 256, 0, stream>>>(qb, kb, vt, aob);

    // output projection
    gemm_bf16<<<dim3(DIM / 128, MROWS / 128), 256, 0, stream>>>(aob, Wot, out,
                                                                DIM, DIM);
}

// Round 7
// 325.943 us; speedup vs baseline: 1.2098x; 1.0653x over previous
//
#include <hip/hip_runtime.h>

#define DIM 2048
#define NH 16
#define HD 128
#define BB 2
#define LL 2048
#define MROWS (BB * LL)   // 4096
#define NKV 2304          // 2048 q + 128 k + 128 v

typedef __attribute__((ext_vector_type(8))) short short8;
typedef __attribute__((ext_vector_type(4))) float floatx4;

__device__ inline ushort f2bf(float f) {
    union { float f; unsigned u; } v; v.f = f;
    unsigned r = v.u + 0x7FFFu + ((v.u >> 16) & 1u);
    return (ushort)(r >> 16);
}

#define GL16(g, l)                                                         \
    __builtin_amdgcn_global_load_lds(                                      \
        (const __attribute__((address_space(1))) unsigned int*)(g),        \
        (__attribute__((address_space(3))) unsigned int*)(l), 16, 0, 0)

// ---------------------------------------------------------------------------
// elementwise f32 -> bf16 (8 elems/thread)
// ---------------------------------------------------------------------------
__global__ __launch_bounds__(256) void conv_bf16(const float* __restrict__ in,
                                                 ushort* __restrict__ out) {
    size_t i = ((size_t)blockIdx.x * 256 + threadIdx.x) * 8;
    float4 a = *reinterpret_cast<const float4*>(in + i);
    float4 b = *reinterpret_cast<const float4*>(in + i + 4);
    ushort o[8] = {f2bf(a.x), f2bf(a.y), f2bf(a.z), f2bf(a.w),
                   f2bf(b.x), f2bf(b.y), f2bf(b.z), f2bf(b.w)};
    *reinterpret_cast<uint4*>(out + i) = *reinterpret_cast<uint4*>(o);
}

// ---------------------------------------------------------------------------
// merged weight prep: transpose+convert Wq,Wo,Wk,Wv in one launch.
// ---------------------------------------------------------------------------
__global__ __launch_bounds__(256) void wprep(const float* __restrict__ Wq,
                                             const float* __restrict__ Wk,
                                             const float* __restrict__ Wv,
                                             const float* __restrict__ Wo,
                                             ushort* __restrict__ Wcatt,
                                             ushort* __restrict__ Wot) {
    __shared__ ushort T[64][72];
    const int bid = blockIdx.x;
    const float* in;
    ushort* out;
    int in_ld, c0, r0;
    const int out_ld = 2048;
    if (bid < 1024) {
        in = Wq; out = Wcatt; in_ld = 2048;
        c0 = (bid & 31) * 64; r0 = (bid >> 5) * 64;
    } else if (bid < 2048) {
        int t = bid - 1024;
        in = Wo; out = Wot; in_ld = 2048;
        c0 = (t & 31) * 64; r0 = (t >> 5) * 64;
    } else if (bid < 2112) {
        int t = bid - 2048;
        in = Wk; out = Wcatt + (size_t)2048 * 2048; in_ld = 128;
        c0 = (t & 1) * 64; r0 = (t >> 1) * 64;
    } else {
        int t = bid - 2112;
        in = Wv; out = Wcatt + (size_t)2176 * 2048; in_ld = 128;
        c0 = (t & 1) * 64; r0 = (t >> 1) * 64;
    }
    const int tid = threadIdx.x;
#pragma unroll
    for (int rep = 0; rep < 4; ++rep) {
        int idx = tid + rep * 256;
        int r = idx >> 4, c4 = idx & 15;
        float4 f = *reinterpret_cast<const float4*>(
            in + (size_t)(r0 + r) * in_ld + c0 + c4 * 4);
        T[r][c4 * 4 + 0] = f2bf(f.x);
        T[r][c4 * 4 + 1] = f2bf(f.y);
        T[r][c4 * 4 + 2] = f2bf(f.z);
        T[r][c4 * 4 + 3] = f2bf(f.w);
    }
    __syncthreads();
#pragma unroll
    for (int rep = 0; rep < 4; ++rep) {
        int idx = tid + rep * 256;
        int cr = idx >> 4, rc4 = idx & 15;
        uint a0 = (uint)T[rc4 * 4 + 0][cr] | ((uint)T[rc4 * 4 + 1][cr] << 16);
        uint a1 = (uint)T[rc4 * 4 + 2][cr] | ((uint)T[rc4 * 4 + 3][cr] << 16);
        uint2 val = {a0, a1};
        *reinterpret_cast<uint2*>(
            out + (size_t)(c0 + cr) * out_ld + r0 + rc4 * 4) = val;
    }
}

// ---------------------------------------------------------------------------
// bf16 MFMA GEMM: Y = A @ Bt^T. BM=BN=128, BK=64, 256 threads (4 waves).
// 32 KB LDS, 8x GL16/iter, XOR chunk swizzle (chunk ^ (row&7)).
// ---------------------------------------------------------------------------
__global__ __launch_bounds__(256) void gemm_bf16(const ushort* __restrict__ A,
                                                 const ushort* __restrict__ Bt,
                                                 float* __restrict__ Y,
                                                 int K, int N) {
    __shared__ ushort As[128 * 64];   // 16 KB
    __shared__ ushort Bs[128 * 64];   // 16 KB
    const int tid = threadIdx.x;
    const int lane = tid & 63;
    const int w = tid >> 6;
    const int col = lane & 15, quad = lane >> 4;
    const int m0 = blockIdx.y * 128, n0 = blockIdx.x * 128;
    const int wm = (w >> 1) * 64, wn = (w & 1) * 64;

    floatx4 acc[4][4];
#pragma unroll
    for (int mt = 0; mt < 4; ++mt)
#pragma unroll
        for (int nt = 0; nt < 4; ++nt) acc[mt][nt] = (floatx4){0.f, 0.f, 0.f, 0.f};

    const int sr = tid >> 3;                    // staging row 0..31 (per call)
    const int cg = (tid & 7) ^ (sr & 7);        // swizzled global chunk 0..7
    const int sel = col & 7;                    // read-side unswizzle

    for (int k0 = 0; k0 < K; k0 += 64) {
        __syncthreads();
#pragma unroll
        for (int j = 0; j < 4; ++j)
            GL16(A + (size_t)(m0 + j * 32 + sr) * K + k0 + cg * 8,
                 As + (size_t)(j * 2048 + tid * 8));
#pragma unroll
        for (int j = 0; j < 4; ++j)
            GL16(Bt + (size_t)(n0 + j * 32 + sr) * K + k0 + cg * 8,
                 Bs + (size_t)(j * 2048 + tid * 8));
        __syncthreads();

#pragma unroll
        for (int kk = 0; kk < 2; ++kk) {
            short8 af[4], bf[4];
#pragma unroll
            for (int mt = 0; mt < 4; ++mt)
                af[mt] = *reinterpret_cast<const short8*>(
                    &As[(wm + mt * 16 + col) * 64 +
                        ((kk * 4 + quad) ^ sel) * 8]);
#pragma unroll
            for (int nt = 0; nt < 4; ++nt)
                bf[nt] = *reinterpret_cast<const short8*>(
                    &Bs[(wn + nt * 16 + col) * 64 +
                        ((kk * 4 + quad) ^ sel) * 8]);
#pragma unroll
            for (int mt = 0; mt < 4; ++mt)
#pragma unroll
                for (int nt = 0; nt < 4; ++nt)
                    acc[mt][nt] = __builtin_amdgcn_mfma_f32_16x16x32_bf16(
                        af[mt], bf[nt], acc[mt][nt], 0, 0, 0);
        }
    }

#pragma unroll
    for (int mt = 0; mt < 4; ++mt)
#pragma unroll
        for (int nt = 0; nt < 4; ++nt)
#pragma unroll
            for (int rr = 0; rr < 4; ++rr)
                Y[(size_t)(m0 + wm + mt * 16 + quad * 4 + rr) * N + n0 + wn +
                  nt * 16 + col] = acc[mt][nt][rr];
}

// ---------------------------------------------------------------------------
// RoPE + RMSNorm: fp32 in (token stride in_ld, head stride HD) -> bf16 out.
// ---------------------------------------------------------------------------
__global__ __launch_bounds__(256) void rope_rms_bf16(const float* __restrict__ in,
                                                     ushort* __restrict__ outb,
                                                     const float* __restrict__ cosb,
                                                     const float* __restrict__ sinb,
                                                     int heads, int nrows,
                                                     int in_ld) {
    int row = blockIdx.x * 4 + (threadIdx.x >> 6);
    int lane = threadIdx.x & 63;
    if (row >= nrows) return;
    int token = row / heads, head = row % heads;
    int l = token & (LL - 1);
    const float* p = in + (size_t)token * in_ld + head * HD;
    float x1 = p[lane];
    float x2 = p[lane + 64];
    float c = cosb[l * 64 + lane];
    float s = sinb[l * 64 + lane];
    float o1 = x1 * c + x2 * s;
    float o2 = -x1 * s + x2 * c;
    float ss = o1 * o1 + o2 * o2;
#pragma unroll
    for (int off = 32; off > 0; off >>= 1) ss += __shfl_xor(ss, off);
    float r = rsqrtf(ss * (1.0f / 128.0f) + 1e-6f);
    outb[(size_t)row * HD + lane] = f2bf(o1 * r);
    outb[(size_t)row * HD + lane + 64] = f2bf(o2 * r);
}

// ---------------------------------------------------------------------------
// V transpose + bf16: in f32 (B*L, in_ld) cols 0..127 -> vt (B,128,L) bf16.
// ---------------------------------------------------------------------------
__global__ __launch_bounds__(256) void vtrans(const float* __restrict__ v,
                                              ushort* __restrict__ vt,
                                              int in_ld) {
    __shared__ ushort T[64][72];
    const int l0 = blockIdx.x * 64, d0 = blockIdx.y * 64, b = blockIdx.z;
    const int tid = threadIdx.x;
#pragma unroll
    for (int rep = 0; rep < 4; ++rep) {
        int idx = tid + rep * 256;
        int r = idx >> 4, c4 = idx & 15;
        float4 f = *reinterpret_cast<const float4*>(
            v + (size_t)(b * LL + l0 + r) * in_ld + d0 + c4 * 4);
        T[r][c4 * 4 + 0] = f2bf(f.x);
        T[r][c4 * 4 + 1] = f2bf(f.y);
        T[r][c4 * 4 + 2] = f2bf(f.z);
        T[r][c4 * 4 + 3] = f2bf(f.w);
    }
    __syncthreads();
#pragma unroll
    for (int rep = 0; rep < 4; ++rep) {
        int idx = tid + rep * 256;
        int dr = idx >> 4, lc4 = idx & 15;
        uint a0 = (uint)T[lc4 * 4 + 0][dr] | ((uint)T[lc4 * 4 + 1][dr] << 16);
        uint a1 = (uint)T[lc4 * 4 + 2][dr] | ((uint)T[lc4 * 4 + 3][dr] << 16);
        uint2 val = {a0, a1};
        *reinterpret_cast<uint2*>(
            vt + (size_t)(b * HD + d0 + dr) * LL + l0 + lc4 * 4) = val;
    }
}

// ---------------------------------------------------------------------------
// Flash-style causal MQA attention, bf16 MFMA 16x16x32, load-balanced pairs.
// FIXED-MAX softmax: RMS-normed q,k bound scaled scores by sqrt(128)=11.31
// (Cauchy-Schwarz; bf16 rounding < +0.5%) -> constant max M=11.5, no running
// max / alpha / O-rescale. K/V tiles staged via GL16 with XOR chunk swizzle.
// ---------------------------------------------------------------------------
__global__ __launch_bounds__(256) void flash_mfma(const ushort* __restrict__ qb,
                                                  const ushort* __restrict__ kb,
                                                  const ushort* __restrict__ vt,
                                                  ushort* __restrict__ aob) {
    __shared__ ushort Ks[64 * 128];    // 16 KB, swizzled 16B chunks
    __shared__ ushort VTs[128 * 64];   // 16 KB, swizzled 16B chunks
    __shared__ ushort Ps[4][16][72];   // 9 KB, per-wave P buffer

    const int tid = threadIdx.x;
    const int w = tid >> 6, lane = tid & 63;
    const int col = lane & 15, quad = lane >> 4;
    const int pairIdx = blockIdx.x, bh = blockIdx.y;
    const int b = bh >> 4, h = bh & 15;
    const int sel = col & 7;  // read-side unswizzle (tile rows == col mod 8)
    // p = exp2(s*scl2 - M2), M2 = 11.5*log2e
    const float scl2 = 0.08838834764831845f * 1.44269504088896340736f;
    const float M2 = 11.5f * 1.44269504088896340736f;

    // K staging: slot s (16B) -> row=s>>4, glob chunk=(s&15)^(row&7)
    const int ksr[4] = {(tid + 0) >> 4, (tid + 256) >> 4, (tid + 512) >> 4,
                        (tid + 768) >> 4};
    // V staging: slot s -> row=s>>3, glob chunk=(s&7)^(row&7)
    const int vsr[4] = {(tid + 0) >> 3, (tid + 256) >> 3, (tid + 512) >> 3,
                        (tid + 768) >> 3};

    for (int sp = 0; sp < 2; ++sp) {
        const int qt = sp ? (31 - pairIdx) : pairIdx;
        const int q0 = qt * 64;

        const ushort* qrow =
            qb + ((size_t)(b * LL + q0 + w * 16 + col) * NH + h) * HD;
        short8 aq[4];
#pragma unroll
        for (int kc = 0; kc < 4; ++kc)
            aq[kc] = *reinterpret_cast<const short8*>(qrow + kc * 32 + quad * 8);

        float lrow[4] = {0.f, 0.f, 0.f, 0.f};
        floatx4 oacc[8];
#pragma unroll
        for (int dt = 0; dt < 8; ++dt) oacc[dt] = (floatx4){0.f, 0.f, 0.f, 0.f};

        const int ntiles = qt + 1;
        for (int kt = 0; kt < ntiles; ++kt) {
            const int k0 = kt * 64;
            __syncthreads();
            // ---- stage K tile 64x128 via GL16 (swizzled) ----
#pragma unroll
            for (int rep = 0; rep < 4; ++rep) {
                int slot = tid + rep * 256;
                int r = ksr[rep];
                int gc = (slot & 15) ^ (r & 7);
                GL16(kb + (size_t)(b * LL + k0 + r) * HD + gc * 8,
                     Ks + (size_t)slot * 8);
            }
            // ---- stage V^T tile 128x64 via GL16 (swizzled) ----
#pragma unroll
            for (int rep = 0; rep < 4; ++rep) {
                int slot = tid + rep * 256;
                int r = vsr[rep];
                int gc = (slot & 7) ^ (r & 7);
                GL16(vt + (size_t)(b * HD + r) * LL + k0 + gc * 8,
                     VTs + (size_t)slot * 8);
            }
            __syncthreads();

            // S = Q K^T
            floatx4 sacc[4];
#pragma unroll
            for (int nt = 0; nt < 4; ++nt)
                sacc[nt] = (floatx4){0.f, 0.f, 0.f, 0.f};
#pragma unroll
            for (int nt = 0; nt < 4; ++nt) {
#pragma unroll
                for (int kc = 0; kc < 4; ++kc) {
                    short8 bk = *reinterpret_cast<const short8*>(
                        &Ks[(nt * 16 + col) * 128 +
                            ((kc * 4 + quad) ^ sel) * 8]);
                    sacc[nt] = __builtin_amdgcn_mfma_f32_16x16x32_bf16(
                        aq[kc], bk, sacc[nt], 0, 0, 0);
                }
            }

            // p = exp2(s*scl2 - M2), causal-masked; accumulate per-lane l
            float psum[4] = {0.f, 0.f, 0.f, 0.f};
#pragma unroll
            for (int nt = 0; nt < 4; ++nt) {
                int kj = k0 + nt * 16 + col;
#pragma unroll
                for (int rr = 0; rr < 4; ++rr) {
                    int qi = q0 + w * 16 + quad * 4 + rr;
                    float p = exp2f(fmaf(sacc[nt][rr], scl2, -M2));
                    p = (kj <= qi) ? p : 0.0f;
                    sacc[nt][rr] = p;
                    psum[rr] += p;
                }
            }
#pragma unroll
            for (int rr = 0; rr < 4; ++rr) lrow[rr] += psum[rr];

            // P: C-layout -> LDS -> A-layout (per-wave buffer)
#pragma unroll
            for (int nt = 0; nt < 4; ++nt)
#pragma unroll
                for (int rr = 0; rr < 4; ++rr)
                    Ps[w][quad * 4 + rr][nt * 16 + col] = f2bf(sacc[nt][rr]);
            asm volatile("s_waitcnt lgkmcnt(0)" ::: "memory");

            // O += P V
#pragma unroll
            for (int kt2 = 0; kt2 < 2; ++kt2) {
                short8 ap = *reinterpret_cast<const short8*>(
                    &Ps[w][col][kt2 * 32 + quad * 8]);
#pragma unroll
                for (int dt = 0; dt < 8; ++dt) {
                    short8 bv = *reinterpret_cast<const short8*>(
                        &VTs[(dt * 16 + col) * 64 +
                             ((kt2 * 4 + quad) ^ sel) * 8]);
                    oacc[dt] = __builtin_amdgcn_mfma_f32_16x16x32_bf16(
                        ap, bv, oacc[dt], 0, 0, 0);
                }
            }
        }

        // epilogue: reduce per-lane l across the 16 row lanes, store bf16
#pragma unroll
        for (int off = 1; off < 16; off <<= 1)
#pragma unroll
            for (int rr = 0; rr < 4; ++rr)
                lrow[rr] += __shfl_xor(lrow[rr], off);
        float inv[4];
#pragma unroll
        for (int rr = 0; rr < 4; ++rr) inv[rr] = 1.0f / lrow[rr];
#pragma unroll
        for (int dt = 0; dt < 8; ++dt)
#pragma unroll
            for (int rr = 0; rr < 4; ++rr)
                aob[((size_t)(b * LL + q0 + w * 16 + quad * 4 + rr) * NH + h) *
                        HD + dt * 16 + col] = f2bf(oacc[dt][rr] * inv[rr]);
    }
}

// ---------------------------------------------------------------------------
extern "C" void kernel_launch(void* const* d_in, const int* in_sizes, int n_in,
                              void* d_out, int out_size, void* d_ws,
                              size_t ws_size, hipStream_t stream) {
    const float* x    = (const float*)d_in[0];
    const float* cosb = (const float*)d_in[1];
    const float* sinb = (const float*)d_in[2];
    const float* Wq   = (const float*)d_in[3];
    const float* Wk   = (const float*)d_in[4];
    const float* Wv   = (const float*)d_in[5];
    const float* Wo   = (const float*)d_in[6];
    float* out = (float*)d_out;

    float* qkv  = (float*)d_ws;                         // M*2304 f32
    ushort* xb  = (ushort*)(qkv + (size_t)MROWS * NKV); // M*DIM bf16
    ushort* qb  = xb + (size_t)MROWS * DIM;             // M*DIM bf16
    ushort* kb  = qb + (size_t)MROWS * DIM;             // M*HD bf16
    ushort* vt  = kb + (size_t)MROWS * HD;              // M*HD bf16 (B,D,L)
    ushort* aob = vt + (size_t)MROWS * HD;              // M*DIM bf16
    ushort* Wcatt = aob + (size_t)MROWS * DIM;          // 2304*2048 bf16
    ushort* Wot   = Wcatt + (size_t)NKV * DIM;          // 2048*2048 bf16

    conv_bf16<<<dim3(MROWS * DIM / (256 * 8)), 256, 0, stream>>>(x, xb);
    wprep<<<dim3(2176), 256, 0, stream>>>(Wq, Wk, Wv, Wo, Wcatt, Wot);

    // fused q|k|v projection: (M,2048) @ (2048,2304)
    gemm_bf16<<<dim3(NKV / 128, MROWS / 128), 256, 0, stream>>>(xb, Wcatt, qkv,
                                                                DIM, NKV);

    // RoPE + RMSNorm -> bf16
    rope_rms_bf16<<<dim3(MROWS * NH / 4), 256, 0, stream>>>(
        qkv, qb, cosb, sinb, NH, MROWS * NH, NKV);
    rope_rms_bf16<<<dim3(MROWS / 4), 256, 0, stream>>>(
        qkv + DIM, kb, cosb, sinb, 1, MROWS, NKV);
    vtrans<<<dim3(LL / 64, 2, BB), 256, 0, stream>>>(qkv + DIM + HD, vt, NKV);

    // causal MQA attention
    flash_mfma<<<dim3(LL / 128, BB * NH), 256, 0, stream>>>(qb, kb, vt, aob);

    // output projection
    gemm_bf16<<<dim3(DIM / 128, MROWS / 128), 256, 0, stream>>>(aob, Wot, out,
                                                                DIM, DIM);
}